// Round 13
// baseline (247.494 us; speedup 1.0000x reference)
//
#include <hip/hip_runtime.h>
#include <math.h>

// Problem constants (fixed by reference)
#define B_TOT   256
#define N_TOT   2304
#define IN_DIM  8
#define NC      10      // NUM_CLASSES
#define OD      16      // OUT_DIM
#define CD      160     // NC*OD
#define RBIAS   0.1f

// Tiling: wave-per-class layout. Block = 10 waves (c=0..9) × 64 lanes (b).
#define BTILE    64                      // b per block (= wave lanes)
#define NS       192                     // n-slices (grid.y); grid = 4*192 = 768
#define NPB      (N_TOT / NS)            // 12 n per block (6 pairs)
#define NTHREADS 640                     // 10 waves
#define XR       (NPB * IN_DIM + 4)      // 100: x row stride
#define LB       72                      // logit board row stride
#define NF4      (B_TOT * CD / 4)        // 10240 float4 per partial slab
#define RCOLS    32                      // float4-columns per reduce block
#define RGRPS    8                       // y-groups per reduce block
#define RYPER    (NS / RGRPS)            // 24 slabs per (col, grp) thread

// Routing round, n-PAIRED: two independent W s_load streams per iteration so
// one stream's K$-latency wait overlaps the other's FMA (R12 post-mortem:
// 46% VALUBusy, stall = chunked s_load lgkmcnt waits; round 0 without any
// barriers ran identical 51us -> s_load-latency-bound, not barrier-bound).
// Wave c, lane b; thread owns u[16] for (b0+b, class c); W slice wave-uniform
// -> SGPR operand. Logit boards: 2 double-buffered SETS of 2 boards; one
// barrier per pair (WAR-safe: set p+1 writes different boards than set p
// reads; same-board reuse separated by the intervening barrier).
// FIRST=1: cw uniform -> acc += u, no logits/barriers; 0.1 folded in reduce.
template <int FIRST>
__global__ __launch_bounds__(NTHREADS) void routing_round(
    const float* __restrict__ x,      // [B, N, 8]
    const float* __restrict__ W,      // [N, 8, 160]
    const float* __restrict__ S_acc,  // [B, 160]
    float* __restrict__ part)         // [NS, B, 160]
{
    __shared__ float sh_x[BTILE * XR];            // 25.6 KB
    __shared__ float sh_lg[4][NC * LB];           // 11.5 KB (2 sets × 2 boards)

    const int tid = threadIdx.x;
    const int b0  = blockIdx.x * BTILE;
    const int n0  = blockIdx.y * NPB;
    const int b   = tid & 63;
    const int cu  = __builtin_amdgcn_readfirstlane(tid >> 6);

    // ---- stage x tile: [64 b][96 floats], coalesced float4
    {
        const int XT4 = BTILE * (NPB * IN_DIM / 4);   // 1536
        for (int k = tid; k < XT4; k += NTHREADS) {
            int bb   = k / (NPB * 2);
            int off4 = k - bb * (NPB * 2);
            float4 v = *(const float4*)(x + ((size_t)(b0 + bb) * N_TOT + n0) * IN_DIM + off4 * 4);
            *(float4*)(&sh_x[bb * XR + off4 * 4]) = v;
        }
    }

    // ---- S fragment: all 16 d for (b, c)
    float S[OD];
    if (!FIRST) {
        const float4* sp = (const float4*)(S_acc + (size_t)(b0 + b) * CD + cu * OD);
        #pragma unroll
        for (int q = 0; q < 4; q++) ((float4*)S)[q] = sp[q];
    }

    float acc[OD];
    #pragma unroll
    for (int d = 0; d < OD; d++) acc[d] = 0.f;

    __syncthreads();   // sh_x ready

    const float* Wc = W + cu * OD;    // wave-uniform base

    for (int np = 0; np < NPB; np += 2) {
        // x rows for the pair
        float xfa[IN_DIM], xfb[IN_DIM];
        {
            const float4* xpa = (const float4*)(&sh_x[b * XR + np * IN_DIM]);
            const float4* xpb = (const float4*)(&sh_x[b * XR + (np + 1) * IN_DIM]);
            ((float4*)xfa)[0] = xpa[0];  ((float4*)xfa)[1] = xpa[1];
            ((float4*)xfb)[0] = xpb[0];  ((float4*)xfb)[1] = xpb[1];
        }

        // two independent scalar-load streams, interleaved FMA
        const float* Wa = Wc + (size_t)(n0 + np) * (IN_DIM * CD);
        const float* Wb = Wa + IN_DIM * CD;
        float ua[OD], ub[OD];
        #pragma unroll
        for (int d = 0; d < OD; d++) {
            ua[d] = xfa[0] * Wa[d];
            ub[d] = xfb[0] * Wb[d];
        }
        #pragma unroll
        for (int i = 1; i < IN_DIM; i++) {
            const float* Wai = Wa + i * CD;
            const float* Wbi = Wb + i * CD;
            #pragma unroll
            for (int d = 0; d < OD; d++) ua[d] = fmaf(xfa[i], Wai[d], ua[d]);
            #pragma unroll
            for (int d = 0; d < OD; d++) ub[d] = fmaf(xfb[i], Wbi[d], ub[d]);
        }

        if (!FIRST) {
            const int set = (np >> 1) & 1;     // double-buffered board set
            float lga = 0.f, lgb = 0.f;
            #pragma unroll
            for (int d = 0; d < OD; d++) lga = fmaf(ua[d], S[d], lga);
            #pragma unroll
            for (int d = 0; d < OD; d++) lgb = fmaf(ub[d], S[d], lgb);
            sh_lg[set * 2 + 0][cu * LB + b] = lga;
            sh_lg[set * 2 + 1][cu * LB + b] = lgb;
            __syncthreads();   // one barrier per PAIR

            // softmax a
            {
                const float* brd = sh_lg[set * 2 + 0];
                float m = -1e30f, row[NC];
                #pragma unroll
                for (int k = 0; k < NC; k++) { row[k] = brd[k * LB + b]; m = fmaxf(m, row[k]); }
                float den = 0.f;
                #pragma unroll
                for (int k = 0; k < NC; k++) den += __expf(row[k] - m);
                float cwa = __expf(lga - m) / den;
                #pragma unroll
                for (int d = 0; d < OD; d++) acc[d] = fmaf(cwa, ua[d], acc[d]);
            }
            // softmax b
            {
                const float* brd = sh_lg[set * 2 + 1];
                float m = -1e30f, row[NC];
                #pragma unroll
                for (int k = 0; k < NC; k++) { row[k] = brd[k * LB + b]; m = fmaxf(m, row[k]); }
                float den = 0.f;
                #pragma unroll
                for (int k = 0; k < NC; k++) den += __expf(row[k] - m);
                float cwb = __expf(lgb - m) / den;
                #pragma unroll
                for (int d = 0; d < OD; d++) acc[d] = fmaf(cwb, ub[d], acc[d]);
            }
        } else {
            #pragma unroll
            for (int d = 0; d < OD; d++) acc[d] += ua[d] + ub[d];
        }
    }

    float* dst = part + ((size_t)blockIdx.y * B_TOT + (b0 + b)) * CD + cu * OD;
    #pragma unroll
    for (int q = 0; q < 4; q++)
        ((float4*)dst)[q] = ((float4*)acc)[q];
}

// ===== Full-device merged reduce (R12, proven): 320 blocks × 256 threads.
// Block owns 32 float4-columns; thread (col, grp) sums 24 slabs; LDS combine;
// threads 0..31 apply scale/bias + stage B: store S_acc (round 0 — no
// memset), add (round 1), squash -> v_out (round 2).
__global__ __launch_bounds__(256) void reduce_round(
    const float* __restrict__ part,   // [NS, B, 160]
    float* __restrict__ S_acc,        // [B, 160]
    float* __restrict__ v_out,        // [B, 10, 16]
    float scale, int round)
{
    __shared__ float4 sh[RGRPS][RCOLS];   // 4 KB

    const int col = threadIdx.x & (RCOLS - 1);
    const int grp = threadIdx.x >> 5;               // 0..7
    const int g   = blockIdx.x * RCOLS + col;       // float4 column index

    const float4* p4 = (const float4*)part + (size_t)grp * NF4 + g;
    float4 s = { 0.f, 0.f, 0.f, 0.f };
    #pragma unroll 4
    for (int y = 0; y < RYPER; y++) {               // slabs grp, grp+8, ...
        float4 t = p4[(size_t)y * RGRPS * NF4];
        s.x += t.x; s.y += t.y; s.z += t.z; s.w += t.w;
    }
    sh[grp][col] = s;
    __syncthreads();

    if (threadIdx.x < RCOLS) {
        float4 t = { 0.f, 0.f, 0.f, 0.f };
        #pragma unroll
        for (int k = 0; k < RGRPS; k++) {
            float4 q = sh[k][col];
            t.x += q.x; t.y += q.y; t.z += q.z; t.w += q.w;
        }
        t.x = t.x * scale + RBIAS;
        t.y = t.y * scale + RBIAS;
        t.z = t.z * scale + RBIAS;
        t.w = t.w * scale + RBIAS;

        if (round == 0) {
            ((float4*)S_acc)[g] = t;          // store — no memset required
        } else if (round == 1) {
            float4 o = ((float4*)S_acc)[g];
            o.x += t.x; o.y += t.y; o.z += t.z; o.w += t.w;
            ((float4*)S_acc)[g] = o;
        } else {
            // squash: 16 d = 4 consecutive float4 columns = lanes 4k..4k+3
            float ss = t.x * t.x + t.y * t.y + t.z * t.z + t.w * t.w;
            ss += __shfl_xor(ss, 1, 64);
            ss += __shfl_xor(ss, 2, 64);
            float norm = sqrtf(ss);
            float k2 = norm / (1.0f + ss);
            float4 v = { t.x * k2, t.y * k2, t.z * k2, t.w * k2 };
            ((float4*)v_out)[g] = v;
        }
    }
}

extern "C" void kernel_launch(void* const* d_in, const int* in_sizes, int n_in,
                              void* d_out, int out_size, void* d_ws, size_t ws_size,
                              hipStream_t stream) {
    const float* x = (const float*)d_in[0];   // [256,2304,8]
    const float* W = (const float*)d_in[1];   // [2304,8,160]
    float* out = (float*)d_out;               // [256,10,16]

    // Workspace (every byte written before read each call — re-poison safe)
    float* part  = (float*)d_ws;                            // NS * 40960  (~31.5 MB)
    float* S_acc = part + (size_t)NS * B_TOT * CD;          // 40960 floats

    const dim3 rgrid(B_TOT / BTILE, NS);
    const int  RG = NF4 / RCOLS;   // 320 reduce blocks — spans the device

    // Round 0 (uniform cw; 0.1 folded into reduce scale; S_acc stored not added)
    routing_round<1><<<rgrid, NTHREADS, 0, stream>>>(x, W, S_acc, part);
    reduce_round<<<RG, 256, 0, stream>>>(part, S_acc, out, 0.1f, 0);

    // Round 1
    routing_round<0><<<rgrid, NTHREADS, 0, stream>>>(x, W, S_acc, part);
    reduce_round<<<RG, 256, 0, stream>>>(part, S_acc, out, 1.0f, 1);

    // Round 2 (+final squash fused)
    routing_round<0><<<rgrid, NTHREADS, 0, stream>>>(x, W, S_acc, part);
    reduce_round<<<RG, 256, 0, stream>>>(part, S_acc, out, 1.0f, 2);
}